// Round 8
// baseline (128.665 us; speedup 1.0000x reference)
//
#include <hip/hip_runtime.h>
#include <cstdint>
#include <cstddef>

#define B_ 8
#define C_ 10
#define HW_ 65536
#define NPIX_ (B_ * HW_)
#define NB1_ 2048   // K1: 2048 blocks * 256 = 1 px/thread
#define NB2_ 1024   // K2: grid-stride over compacted count (~262k)
#define ROWS_ 2048  // partial-row stride in d_ws

__device__ __forceinline__ float sl1f(float p, float t) {
    float d = fabsf(p - t);
    return (d < 1.0f) ? 0.5f * d * d : d - 0.5f;
}
__device__ __forceinline__ void pinf(float v)  { asm volatile("" :: "v"(v)); }
__device__ __forceinline__ void pini(int v)    { asm volatile("" :: "v"(v)); }

// ============================================================================
// K1: focal + smooth-L1(z,h,vel) + BCE + pos count, over ALL pixels.
// Also compacts positive pixel indices into `list` (wave-aggregated atomic).
// Writes part rows 0,2,3,4,5,6.
// ============================================================================
__global__ __launch_bounds__(256) void bev_loss_cls(
    const float* __restrict__ cls_pred, const float* __restrict__ reg_pred,
    const float* __restrict__ iou_pred, const int* __restrict__ cls_tg,
    const float* __restrict__ reg_tg, const float* __restrict__ reg_w,
    const float* __restrict__ iou_tg, double* __restrict__ part,
    unsigned int* __restrict__ counter, unsigned int* __restrict__ list)
{
    int n  = blockIdx.x * blockDim.x + threadIdx.x;
    int b  = n >> 16;
    int hw = n & 65535;

    // ---- loads, issued up-front ----
    float lg[C_];
    {
        const float* cp = cls_pred + (size_t)b * C_ * HW_ + hw;
        #pragma unroll
        for (int c = 0; c < C_; c++) lg[c] = cp[(size_t)c * HW_];
    }
    const float* rp = reg_pred + (size_t)b * 9 * HW_ + hw;
    const float* rt = reg_tg  + (size_t)b * 9 * HW_ + hw;
    float p2 = rp[2 * HW_], p5 = rp[5 * HW_], p7 = rp[7 * HW_], p8 = rp[8 * HW_];
    float t2 = rt[2 * HW_], t5 = rt[5 * HW_], t7 = rt[7 * HW_], t8 = rt[8 * HW_];
    int   ct = cls_tg[n];
    float w  = reg_w[n];
    float xi = iou_pred[n];
    float yi = iou_tg[n];

    #pragma unroll
    for (int c = 0; c < C_; c++) pinf(lg[c]);
    pinf(p2); pinf(p5); pinf(p7); pinf(p8);
    pinf(t2); pinf(t5); pinf(t7); pinf(t8);
    pini(ct); pinf(w); pinf(xi); pinf(yi);

    int lane = threadIdx.x & 63;
    int wv   = threadIdx.x >> 6;

    // ---- compact positive indices (one atomic per wave) ----
    bool posb = (w > 0.f);
    {
        unsigned long long m = __ballot(posb);
        int cnt    = __popcll(m);
        int prefix = __popcll(m & ((1ULL << lane) - 1ULL));
        unsigned base = 0;
        if (lane == 0 && cnt > 0) base = atomicAdd(counter, (unsigned)cnt);
        base = (unsigned)__shfl((int)base, 0, 64);
        if (posb) list[base + prefix] = (unsigned)n;
    }

    // ---- focal loss ----
    float a0;
    {
        float m = lg[0];
        #pragma unroll
        for (int c = 1; c < C_; c++) m = fmaxf(m, lg[c]);
        int tl = ct < 0 ? 0 : (ct > C_ - 1 ? C_ - 1 : ct);
        float se = 0.f, et = 0.f;
        #pragma unroll
        for (int c = 0; c < C_; c++) {
            float e = __expf(lg[c] - m);
            se += e;
            et = (c == tl) ? e : et;
        }
        float pt = __fdividef(et, se);
        pt = fminf(fmaxf(pt, 1e-7f), 1.0f - 1e-7f);
        float alpha_t = (ct > 0) ? 0.25f : 0.75f;
        float omp = 1.0f - pt;
        float fl = -alpha_t * omp * omp * __logf(pt);
        a0 = (ct >= 0) ? fl : 0.0f;
    }

    float pos = posb ? 1.f : 0.f;
    float a2 = sl1f(p2, t2) * pos;
    float a3 = sl1f(p5, t5) * pos;
    float a4 = (sl1f(p7, t7) + sl1f(p8, t8)) * pos;
    float bce = fmaxf(xi, 0.f) - xi * yi + __logf(1.0f + __expf(-fabsf(xi)));
    float a5 = bce * pos;

    // ---- block reduction (6 rows) ----
    const int kid[6] = { 0, 2, 3, 4, 5, 6 };
    double av[6] = { (double)a0, (double)a2, (double)a3,
                     (double)a4, (double)a5, (double)pos };
    __shared__ double red[6][4];
    #pragma unroll
    for (int k = 0; k < 6; k++) {
        double s = av[k];
        for (int off = 32; off > 0; off >>= 1) s += __shfl_down(s, off, 64);
        if (lane == 0) red[k][wv] = s;
    }
    __syncthreads();
    if (threadIdx.x == 0) {
        #pragma unroll
        for (int k = 0; k < 6; k++)
            part[(size_t)kid[k] * ROWS_ + blockIdx.x] = red[k][0] + red[k][1] + red[k][2] + red[k][3];
    }
}

// ============================================================================
// K2: corners + clip IoU + DIoU, ONLY for compacted positive pixels (~50%).
// Writes part row 1 (one partial per block).
// ============================================================================
__global__ __launch_bounds__(256) void bev_loss_iou(
    const float* __restrict__ reg_pred, const float* __restrict__ reg_tg,
    const unsigned int* __restrict__ counter, const unsigned int* __restrict__ list,
    double* __restrict__ part)
{
    int count  = (int)*counter;
    int stride = gridDim.x * blockDim.x;
    double acc = 0.0;

    for (int i = blockIdx.x * blockDim.x + threadIdx.x; i < count; i += stride) {
        int n  = (int)list[i];
        int b  = n >> 16;
        int hw = n & 65535;

        const float* rp = reg_pred + (size_t)b * 9 * HW_ + hw;
        const float* rt = reg_tg  + (size_t)b * 9 * HW_ + hw;
        float p0 = rp[0 * HW_], p1 = rp[1 * HW_], p3 = rp[3 * HW_], p4 = rp[4 * HW_], p6 = rp[6 * HW_];
        float t0_ = rt[0 * HW_], t1_ = rt[1 * HW_], t3 = rt[3 * HW_], t4 = rt[4 * HW_], t6 = rt[6 * HW_];
        pinf(p0); pinf(p1); pinf(p3); pinf(p4); pinf(p6);
        pinf(t0_); pinf(t1_); pinf(t3); pinf(t4); pinf(t6);

        // ---- corners ----
        float Ax[4], Ay[4], Bx[4], By[4];
        {
            const float sbx[4] = { 1.f, -1.f, -1.f, 1.f };
            const float sby[4] = { -1.f, -1.f, 1.f, 1.f };
            float hx = 0.5f * p3, hy = 0.5f * p4;
            float ss, cc; __sincosf(p6, &ss, &cc);
            #pragma unroll
            for (int q = 0; q < 4; q++) {
                float px = sbx[q] * hx, py = sby[q] * hy;
                Ax[q] = px * cc - py * ss + p0;
                Ay[q] = px * ss + py * cc + p1;
            }
            float hx2 = 0.5f * t3, hy2 = 0.5f * t4;
            float ss2, cc2; __sincosf(t6, &ss2, &cc2);
            #pragma unroll
            for (int q = 0; q < 4; q++) {
                float px = sbx[q] * hx2, py = sby[q] * hy2;
                Bx[q] = px * cc2 - py * ss2 + t0_;
                By[q] = px * ss2 + py * cc2 + t1_;
            }
        }

        // ---- signed areas + signs ----
        float sa = 0.f, sb = 0.f;
        #pragma unroll
        for (int q = 0; q < 4; q++) {
            int j = (q + 1) & 3;
            sa += Ax[q] * Ay[j] - Ay[q] * Ax[j];
            sb += Bx[q] * By[j] - By[q] * Bx[j];
        }
        sa *= 0.5f; sb *= 0.5f;
        float sgnA = (sa > 0.f) ? 1.f : ((sa < 0.f) ? -1.f : 0.f);
        float sgnB = (sb > 0.f) ? 1.f : ((sb < 0.f) ? -1.f : 0.f);

        // ---- Green's-theorem clip, branchless ----
        float S = 0.f;
        {
            float dB[4][4];
            #pragma unroll
            for (int j = 0; j < 4; j++) {
                int j1 = (j + 1) & 3;
                float sx = sgnB * (Bx[j1] - Bx[j]);
                float sy = sgnB * (By[j1] - By[j]);
                float kj = sx * By[j] - sy * Bx[j];
                #pragma unroll
                for (int q = 0; q < 4; q++)
                    dB[j][q] = sx * Ay[q] - sy * Ax[q] - kj;
            }
            #pragma unroll
            for (int q = 0; q < 4; q++) {
                int q1 = (q + 1) & 3;
                float t0 = 0.f, t1 = 1.f;
                #pragma unroll
                for (int j = 0; j < 4; j++) {
                    float d0 = dB[j][q], d1 = dB[j][q1];
                    float den = d1 - d0;
                    float t = __fdividef(-d0, den);
                    float lo = (den > 0.f) ? t : ((den == 0.f && d0 < 0.f) ? 2.f : 0.f);
                    float hi = (den < 0.f) ? t : 1.f;
                    t0 = fmaxf(t0, lo);
                    t1 = fminf(t1, hi);
                }
                S += (Ax[q] * Ay[q1] - Ay[q] * Ax[q1]) * fmaxf(t1 - t0, 0.f);
            }
        }
        {
            float dA[4][4];
            #pragma unroll
            for (int j = 0; j < 4; j++) {
                int j1 = (j + 1) & 3;
                float sx = sgnA * (Ax[j1] - Ax[j]);
                float sy = sgnA * (Ay[j1] - Ay[j]);
                float kj = sx * Ay[j] - sy * Ax[j];
                #pragma unroll
                for (int q = 0; q < 4; q++)
                    dA[j][q] = sx * By[q] - sy * Bx[q] - kj;
            }
            #pragma unroll
            for (int q = 0; q < 4; q++) {
                int q1 = (q + 1) & 3;
                float t0 = 0.f, t1 = 1.f;
                #pragma unroll
                for (int j = 0; j < 4; j++) {
                    float d0 = dA[j][q], d1 = dA[j][q1];
                    float den = d1 - d0;
                    float t = __fdividef(-d0, den);
                    float lo = (den > 0.f) ? t : ((den == 0.f && d0 < 0.f) ? 2.f : 0.f);
                    float hi = (den < 0.f) ? t : 1.f;
                    t0 = fmaxf(t0, lo);
                    t1 = fminf(t1, hi);
                }
                S += (Bx[q] * By[q1] - By[q] * Bx[q1]) * fmaxf(t1 - t0, 0.f);
            }
        }
        float inter = 0.5f * fabsf(S);
        float areaA = fabsf(sa), areaB = fabsf(sb);
        float uni = areaA + areaB - inter;
        float iou = (uni > 1e-7f) ? __fdividef(inter, uni) : 0.f;

        // ---- DIoU-style bev loss (pos == 1 guaranteed) ----
        float ddx = p0 - t0_, ddy = p1 - t1_;
        float d2 = fmaf(ddx, ddx, ddy * ddy);
        float mnx = Ax[0], mxx = Ax[0], mny = Ay[0], mxy = Ay[0];
        #pragma unroll
        for (int q = 1; q < 4; q++) {
            mnx = fminf(mnx, Ax[q]); mxx = fmaxf(mxx, Ax[q]);
            mny = fminf(mny, Ay[q]); mxy = fmaxf(mxy, Ay[q]);
        }
        #pragma unroll
        for (int q = 0; q < 4; q++) {
            mnx = fminf(mnx, Bx[q]); mxx = fmaxf(mxx, Bx[q]);
            mny = fminf(mny, By[q]); mxy = fmaxf(mxy, By[q]);
        }
        float exd = mxx - mnx, eyd = mxy - mny;
        float c2 = fmaxf(fmaf(exd, exd, eyd * eyd), 1e-7f);

        float rp_ = __fdividef(p4, fmaxf(p3, 1e-7f));
        float rt_ = __fdividef(t4, fmaxf(t3, 1e-7f));
        float dv = atanf(__fdividef(rp_ - rt_, fmaf(rp_, rt_, 1.f)));
        float v = 0.4052847345693511f * dv * dv;
        float alpha_c = __fdividef(v, 1.0f - iou + v + 1e-7f);
        acc += (double)(1.0f - iou + __fdividef(d2, c2) + alpha_c * v);
    }

    // ---- block reduction (row 1) ----
    __shared__ double red[4];
    int lane = threadIdx.x & 63;
    int wv   = threadIdx.x >> 6;
    double s = acc;
    for (int off = 32; off > 0; off >>= 1) s += __shfl_down(s, off, 64);
    if (lane == 0) red[wv] = s;
    __syncthreads();
    if (threadIdx.x == 0)
        part[(size_t)1 * ROWS_ + blockIdx.x] = red[0] + red[1] + red[2] + red[3];
}

// ============================================================================
// Finalize: 1 block x 1024 threads.
// ============================================================================
__global__ __launch_bounds__(1024) void bev_loss_fin(
    const double* __restrict__ part, float* __restrict__ out)
{
    int t = threadIdx.x;  // 0..1023
    double v[7];
    #pragma unroll
    for (int k = 0; k < 7; k++) {
        if (k == 1)
            v[k] = part[(size_t)k * ROWS_ + t];                 // K2: 1024 partials
        else
            v[k] = part[(size_t)k * ROWS_ + t] + part[(size_t)k * ROWS_ + 1024 + t];
    }

    int lane = t & 63, wv = t >> 6;
    __shared__ double red[7][16];
    #pragma unroll
    for (int k = 0; k < 7; k++) {
        double s = v[k];
        for (int off = 32; off > 0; off >>= 1) s += __shfl_down(s, off, 64);
        if (lane == 0) red[k][wv] = s;
    }
    __syncthreads();
    if (t == 0) {
        double tot[7];
        #pragma unroll
        for (int k = 0; k < 7; k++) {
            double s = 0.0;
            #pragma unroll
            for (int i = 0; i < 16; i++) s += red[k][i];
            tot[k] = s;
        }
        double npos = fmax(tot[6], 1.0);
        #pragma unroll
        for (int k = 0; k < 6; k++) out[k] = (float)(tot[k] / npos);
    }
}

extern "C" void kernel_launch(void* const* d_in, const int* in_sizes, int n_in,
                              void* d_out, int out_size, void* d_ws, size_t ws_size,
                              hipStream_t stream) {
    const float* cls_pred = (const float*)d_in[0];
    const float* reg_pred = (const float*)d_in[1];
    const float* iou_pred = (const float*)d_in[2];
    const int*   cls_tg   = (const int*)d_in[3];
    const float* reg_tg   = (const float*)d_in[4];
    const float* reg_w    = (const float*)d_in[5];
    const float* iou_tg   = (const float*)d_in[6];
    float* out = (float*)d_out;

    // d_ws layout: [7*ROWS_ doubles partials][counter u32 (16B-aligned slot)][list u32 * NPIX_]
    double* part = (double*)d_ws;
    unsigned int* counter = (unsigned int*)((char*)d_ws + (size_t)7 * ROWS_ * sizeof(double));
    unsigned int* list    = counter + 4;   // 16 bytes after counter

    hipMemsetAsync(counter, 0, sizeof(unsigned int), stream);

    bev_loss_cls<<<NB1_, 256, 0, stream>>>(cls_pred, reg_pred, iou_pred, cls_tg,
                                           reg_tg, reg_w, iou_tg, part, counter, list);
    bev_loss_iou<<<NB2_, 256, 0, stream>>>(reg_pred, reg_tg, counter, list, part);
    bev_loss_fin<<<1, 1024, 0, stream>>>(part, out);
}

// Round 9
// 35.261 us; speedup vs baseline: 3.6489x; 3.6489x over previous
//
#include <hip/hip_runtime.h>
#include <cstdint>
#include <cstddef>

#define B_ 8
#define C_ 10
#define HW_ 65536
#define NPIX_ (B_ * HW_)
#define NB_ 2048   // 2048 blocks * 256 threads = 524288 = 1 px/thread
#define NCH_ 28    // 10 cls + 9 reg_pred + 9 reg_tg channels staged in LDS

__device__ __forceinline__ float sl1f(float p, float t) {
    float d = fabsf(p - t);
    return (d < 1.0f) ? 0.5f * d * d : d - 0.5f;
}

__global__ __launch_bounds__(256) void bev_loss_main(
    const float* __restrict__ cls_pred, const float* __restrict__ reg_pred,
    const float* __restrict__ iou_pred, const int* __restrict__ cls_tg,
    const float* __restrict__ reg_tg, const float* __restrict__ reg_w,
    const float* __restrict__ iou_tg, double* __restrict__ part)
{
    __shared__ float sch[NCH_][256];   // 28 KB

    int tid  = threadIdx.x;
    int lane = tid & 63;
    int wv   = tid >> 6;
    int n0   = blockIdx.x << 8;        // first pixel of this block
    int b    = n0 >> 16;
    int hw0  = n0 & 65535;             // multiple of 256: float4-aligned
    int n    = n0 + tid;

    // ================= Phase 1: cooperative bulk staging =================
    // Each wave stages 7 of the 28 channels; one global_load_dwordx4 covers
    // a whole channel (64 lanes x 4 floats = 256 px). All 7 loads are
    // independent -> fully overlapped L2/HBM latency.
    #pragma unroll
    for (int k = 0; k < 7; k++) {
        int c = wv + 4 * k;            // wave-uniform channel id
        const float* src;
        if (c < 10)      src = cls_pred + ((size_t)(b * C_ + c)) * HW_ + hw0;
        else if (c < 19) src = reg_pred + ((size_t)(b * 9 + (c - 10))) * HW_ + hw0;
        else             src = reg_tg  + ((size_t)(b * 9 + (c - 19))) * HW_ + hw0;
        float4 v = *reinterpret_cast<const float4*>(src + lane * 4);
        *reinterpret_cast<float4*>(&sch[c][lane * 4]) = v;
    }
    // direct per-pixel loads (contiguous streams, 4 independent loads)
    int   ct = cls_tg[n];
    float w  = reg_w[n];
    float xi = iou_pred[n];
    float yi = iou_tg[n];
    __syncthreads();

    // ================= Phase 2: per-pixel compute from LDS =================
    // ---- focal loss ----
    float a0;
    {
        float m = sch[0][tid];
        #pragma unroll
        for (int c = 1; c < C_; c++) m = fmaxf(m, sch[c][tid]);
        int tl = ct < 0 ? 0 : (ct > C_ - 1 ? C_ - 1 : ct);
        float se = 0.f, et = 0.f;
        #pragma unroll
        for (int c = 0; c < C_; c++) {
            float e = __expf(sch[c][tid] - m);
            se += e;
            et = (c == tl) ? e : et;
        }
        float pt = __fdividef(et, se);
        pt = fminf(fmaxf(pt, 1e-7f), 1.0f - 1e-7f);
        float alpha_t = (ct > 0) ? 0.25f : 0.75f;
        float omp = 1.0f - pt;
        float fl = -alpha_t * omp * omp * __logf(pt);
        a0 = (ct >= 0) ? fl : 0.0f;
    }

    float pos = (w > 0.f) ? 1.f : 0.f;

    // reg channels from LDS (cheap re-issuable reads)
    float p0 = sch[10][tid], p1 = sch[11][tid], p2 = sch[12][tid];
    float p3 = sch[13][tid], p4 = sch[14][tid], p5 = sch[15][tid];
    float p6 = sch[16][tid], p7 = sch[17][tid], p8 = sch[18][tid];
    float t0_ = sch[19][tid], t1_ = sch[20][tid], t2 = sch[21][tid];
    float t3  = sch[22][tid], t4  = sch[23][tid], t5 = sch[24][tid];
    float t6  = sch[25][tid], t7  = sch[26][tid], t8 = sch[27][tid];

    // ---- corners ----
    float Ax[4], Ay[4], Bx[4], By[4];
    {
        const float sbx[4] = { 1.f, -1.f, -1.f, 1.f };
        const float sby[4] = { -1.f, -1.f, 1.f, 1.f };
        float hx = 0.5f * p3, hy = 0.5f * p4;
        float ss, cc; __sincosf(p6, &ss, &cc);
        #pragma unroll
        for (int i = 0; i < 4; i++) {
            float px = sbx[i] * hx, py = sby[i] * hy;
            Ax[i] = px * cc - py * ss + p0;
            Ay[i] = px * ss + py * cc + p1;
        }
        float hx2 = 0.5f * t3, hy2 = 0.5f * t4;
        float ss2, cc2; __sincosf(t6, &ss2, &cc2);
        #pragma unroll
        for (int i = 0; i < 4; i++) {
            float px = sbx[i] * hx2, py = sby[i] * hy2;
            Bx[i] = px * cc2 - py * ss2 + t0_;
            By[i] = px * ss2 + py * cc2 + t1_;
        }
    }

    // ---- signed areas + orientation signs ----
    float sa = 0.f, sb = 0.f;
    #pragma unroll
    for (int i = 0; i < 4; i++) {
        int j = (i + 1) & 3;
        sa += Ax[i] * Ay[j] - Ay[i] * Ax[j];
        sb += Bx[i] * By[j] - By[i] * Bx[j];
    }
    sa *= 0.5f; sb *= 0.5f;
    float sgnA = (sa > 0.f) ? 1.f : ((sa < 0.f) ? -1.f : 0.f);
    float sgnB = (sb > 0.f) ? 1.f : ((sb < 0.f) ? -1.f : 0.f);

    // ---- rotated IoU: Green's-theorem clip, branchless ----
    float S = 0.f;
    {
        float dB[4][4];
        #pragma unroll
        for (int j = 0; j < 4; j++) {
            int j1 = (j + 1) & 3;
            float sx = sgnB * (Bx[j1] - Bx[j]);
            float sy = sgnB * (By[j1] - By[j]);
            float kj = sx * By[j] - sy * Bx[j];
            #pragma unroll
            for (int i = 0; i < 4; i++)
                dB[j][i] = sx * Ay[i] - sy * Ax[i] - kj;
        }
        #pragma unroll
        for (int i = 0; i < 4; i++) {
            int i1 = (i + 1) & 3;
            float t0 = 0.f, t1 = 1.f;
            #pragma unroll
            for (int j = 0; j < 4; j++) {
                float d0 = dB[j][i], d1 = dB[j][i1];
                float den = d1 - d0;
                float t = __fdividef(-d0, den);
                float lo = (den > 0.f) ? t : ((den == 0.f && d0 < 0.f) ? 2.f : 0.f);
                float hi = (den < 0.f) ? t : 1.f;
                t0 = fmaxf(t0, lo);
                t1 = fminf(t1, hi);
            }
            S += (Ax[i] * Ay[i1] - Ay[i] * Ax[i1]) * fmaxf(t1 - t0, 0.f);
        }
    }
    {
        float dA[4][4];
        #pragma unroll
        for (int j = 0; j < 4; j++) {
            int j1 = (j + 1) & 3;
            float sx = sgnA * (Ax[j1] - Ax[j]);
            float sy = sgnA * (Ay[j1] - Ay[j]);
            float kj = sx * Ay[j] - sy * Ax[j];
            #pragma unroll
            for (int i = 0; i < 4; i++)
                dA[j][i] = sx * By[i] - sy * Bx[i] - kj;
        }
        #pragma unroll
        for (int i = 0; i < 4; i++) {
            int i1 = (i + 1) & 3;
            float t0 = 0.f, t1 = 1.f;
            #pragma unroll
            for (int j = 0; j < 4; j++) {
                float d0 = dA[j][i], d1 = dA[j][i1];
                float den = d1 - d0;
                float t = __fdividef(-d0, den);
                float lo = (den > 0.f) ? t : ((den == 0.f && d0 < 0.f) ? 2.f : 0.f);
                float hi = (den < 0.f) ? t : 1.f;
                t0 = fmaxf(t0, lo);
                t1 = fminf(t1, hi);
            }
            S += (Bx[i] * By[i1] - By[i] * Bx[i1]) * fmaxf(t1 - t0, 0.f);
        }
    }
    float inter = 0.5f * fabsf(S);
    float areaA = fabsf(sa), areaB = fabsf(sb);
    float uni = areaA + areaB - inter;
    float iou = (uni > 1e-7f) ? __fdividef(inter, uni) : 0.f;

    // ---- DIoU-style bev loss ----
    float a1;
    {
        float ddx = p0 - t0_, ddy = p1 - t1_;
        float d2 = fmaf(ddx, ddx, ddy * ddy);
        float mnx = Ax[0], mxx = Ax[0], mny = Ay[0], mxy = Ay[0];
        #pragma unroll
        for (int i = 1; i < 4; i++) {
            mnx = fminf(mnx, Ax[i]); mxx = fmaxf(mxx, Ax[i]);
            mny = fminf(mny, Ay[i]); mxy = fmaxf(mxy, Ay[i]);
        }
        #pragma unroll
        for (int i = 0; i < 4; i++) {
            mnx = fminf(mnx, Bx[i]); mxx = fmaxf(mxx, Bx[i]);
            mny = fminf(mny, By[i]); mxy = fmaxf(mxy, By[i]);
        }
        float exd = mxx - mnx, eyd = mxy - mny;
        float c2 = fmaxf(fmaf(exd, exd, eyd * eyd), 1e-7f);

        // atan(rp) - atan(rt) = atan((rp-rt)/(1+rp*rt))  (both ratios >= 0 here)
        float rp_ = __fdividef(p4, fmaxf(p3, 1e-7f));
        float rt_ = __fdividef(t4, fmaxf(t3, 1e-7f));
        float dv = atanf(__fdividef(rp_ - rt_, fmaf(rp_, rt_, 1.f)));
        float v = 0.4052847345693511f * dv * dv;
        float alpha_c = __fdividef(v, 1.0f - iou + v + 1e-7f);
        float lbev = 1.0f - iou + __fdividef(d2, c2) + alpha_c * v;
        a1 = lbev * pos;
    }

    // ---- smooth-L1 z / h / vel + BCE ----
    float a2 = sl1f(p2, t2) * pos;
    float a3 = sl1f(p5, t5) * pos;
    float a4 = (sl1f(p7, t7) + sl1f(p8, t8)) * pos;
    float bce = fmaxf(xi, 0.f) - xi * yi + __logf(1.0f + __expf(-fabsf(xi)));
    float a5 = bce * pos;

    // ================= block reduction =================
    double av[7] = { (double)a0, (double)a1, (double)a2, (double)a3,
                     (double)a4, (double)a5, (double)pos };
    __shared__ double red[7][4];
    __syncthreads();   // sch no longer needed; reuse LDS space is fine (red is separate)
    #pragma unroll
    for (int k = 0; k < 7; k++) {
        double s = av[k];
        for (int off = 32; off > 0; off >>= 1) s += __shfl_down(s, off, 64);
        if (lane == 0) red[k][wv] = s;
    }
    __syncthreads();
    if (tid == 0) {
        #pragma unroll
        for (int k = 0; k < 7; k++)
            part[(size_t)k * NB_ + blockIdx.x] = red[k][0] + red[k][1] + red[k][2] + red[k][3];
    }
}

// ============================================================================
// Finalize: 1 block x 1024 threads; each thread folds 2 partials per row.
// ============================================================================
__global__ __launch_bounds__(1024) void bev_loss_fin(
    const double* __restrict__ part, float* __restrict__ out)
{
    int t = threadIdx.x;  // 0..1023
    double v[7];
    #pragma unroll
    for (int k = 0; k < 7; k++)
        v[k] = part[(size_t)k * NB_ + t] + part[(size_t)k * NB_ + 1024 + t];

    int lane = t & 63, wv = t >> 6;
    __shared__ double red[7][16];
    #pragma unroll
    for (int k = 0; k < 7; k++) {
        double s = v[k];
        for (int off = 32; off > 0; off >>= 1) s += __shfl_down(s, off, 64);
        if (lane == 0) red[k][wv] = s;
    }
    __syncthreads();
    if (t == 0) {
        double tot[7];
        #pragma unroll
        for (int k = 0; k < 7; k++) {
            double s = 0.0;
            #pragma unroll
            for (int i = 0; i < 16; i++) s += red[k][i];
            tot[k] = s;
        }
        double npos = fmax(tot[6], 1.0);
        #pragma unroll
        for (int k = 0; k < 6; k++) out[k] = (float)(tot[k] / npos);
    }
}

extern "C" void kernel_launch(void* const* d_in, const int* in_sizes, int n_in,
                              void* d_out, int out_size, void* d_ws, size_t ws_size,
                              hipStream_t stream) {
    const float* cls_pred = (const float*)d_in[0];
    const float* reg_pred = (const float*)d_in[1];
    const float* iou_pred = (const float*)d_in[2];
    const int*   cls_tg   = (const int*)d_in[3];
    const float* reg_tg   = (const float*)d_in[4];
    const float* reg_w    = (const float*)d_in[5];
    const float* iou_tg   = (const float*)d_in[6];
    float* out = (float*)d_out;
    double* part = (double*)d_ws;   // 7 * 2048 doubles

    bev_loss_main<<<NB_, 256, 0, stream>>>(cls_pred, reg_pred, iou_pred, cls_tg,
                                           reg_tg, reg_w, iou_tg, part);
    bev_loss_fin<<<1, 1024, 0, stream>>>(part, out);
}